// Round 1
// baseline (450.511 us; speedup 1.0000x reference)
//
#include <hip/hip_runtime.h>
#include <stdint.h>

typedef float f32x4 __attribute__((ext_vector_type(4)));
typedef __bf16 bf16x8 __attribute__((ext_vector_type(8)));
typedef unsigned short u16;
typedef unsigned int u32;

#define INVT 14.285714285714286f   // 1/0.07 ; also the fixed LSE max bound (cos<=1)

__device__ __forceinline__ u16 f2bf(float f) {
  u32 u = __float_as_uint(f);
  u32 r = (u + 0x7fffu + ((u >> 16) & 1u)) >> 16;
  return (u16)r;
}
__device__ __forceinline__ float bf2f(u16 h) { return __uint_as_float(((u32)h) << 16); }

// async global->LDS, 16B per lane (CK-style casts; lane i lands at base + i*16)
__device__ __forceinline__ void g2l16(const void* g, void* l) {
  auto gp = reinterpret_cast<__attribute__((address_space(1))) uint32_t*>(
      reinterpret_cast<uintptr_t>(g));
  auto lp = reinterpret_cast<__attribute__((address_space(3))) uint32_t*>(
      reinterpret_cast<uintptr_t>(l));
  __builtin_amdgcn_global_load_lds(gp, lp, 16, 0, 0);
}

// ---------- fp32 -> bf16 elementwise convert ----------
__global__ __launch_bounds__(256) void k_cvt(const float* __restrict__ in,
                                             u16* __restrict__ out, int n) {
  int i = (blockIdx.x * 256 + threadIdx.x) * 4;
  if (i >= n) return;
  float4 v = *(const float4*)(in + i);
  ushort4 p;
  p.x = f2bf(v.x); p.y = f2bf(v.y); p.z = f2bf(v.z); p.w = f2bf(v.w);
  *(ushort4*)(out + i) = p;
}

// ---------- fp32 [R][C] -> bf16 [C][R] transpose ----------
__global__ __launch_bounds__(256) void k_transpose(const float* __restrict__ in,
                                                   u16* __restrict__ out, int R, int C) {
  __shared__ float t[64][65];
  const int r0 = blockIdx.y * 64, c0 = blockIdx.x * 64;
#pragma unroll
  for (int p = 0; p < 16; ++p) {
    int idx = p * 256 + threadIdx.x;
    int r = idx >> 6, c = idx & 63;
    t[r][c] = in[(size_t)(r0 + r) * C + (c0 + c)];
  }
  __syncthreads();
#pragma unroll
  for (int p = 0; p < 16; ++p) {
    int idx = p * 256 + threadIdx.x;
    int c = idx >> 6, r = idx & 63;
    out[(size_t)(c0 + c) * R + (r0 + r)] = f2bf(t[r][c]);
  }
}

// ---------- bf16 GEMM: C[M][N] = op(A[M][K] @ Bt[N][K]^T + bias), optional relu ----------
__global__ __launch_bounds__(256) void k_gemm(const u16* __restrict__ A, const u16* __restrict__ Bt,
                                              const float* __restrict__ bias, u16* __restrict__ C,
                                              int M, int N, int K, int relu) {
  __shared__ __align__(16) u16 As[128 * 32];
  __shared__ __align__(16) u16 Bs[128 * 32];
  const int tid = threadIdx.x;
  const int l = tid & 63, w = tid >> 6;
  const int wm = w >> 1, wn = w & 1;
  const int m0 = blockIdx.y * 128, n0 = blockIdx.x * 128;

  const int rs = w * 16 + (l >> 2);
  const int kb = (l & 3) * 16;
  const char* gA0 = (const char*)(A + (size_t)(m0 + rs) * K) + kb;
  const char* gA1 = gA0 + (size_t)64 * K * 2;
  const char* gB0 = (const char*)(Bt + (size_t)(n0 + rs) * K) + kb;
  const char* gB1 = gB0 + (size_t)64 * K * 2;
  char* lA0 = (char*)As + w * 1024 + l * 16;
  char* lA1 = lA0 + 4096;
  char* lB0 = (char*)Bs + w * 1024 + l * 16;
  char* lB1 = lB0 + 4096;

  const u16* Af = As + (wm * 64 + (l & 15)) * 32 + (l >> 4) * 8;
  const u16* Bf = Bs + (wn * 64 + (l & 15)) * 32 + (l >> 4) * 8;

  f32x4 acc[4][4] = {};

  for (int k0 = 0; k0 < K; k0 += 32) {
    const int kc = k0 * 2;
    g2l16(gA0 + kc, lA0);
    g2l16(gA1 + kc, lA1);
    g2l16(gB0 + kc, lB0);
    g2l16(gB1 + kc, lB1);
    asm volatile("s_waitcnt vmcnt(0)" ::: "memory");
    __syncthreads();
    bf16x8 af[4], bfr[4];
#pragma unroll
    for (int i = 0; i < 4; ++i) {
      af[i] = *(const bf16x8*)(Af + i * 16 * 32);
      bfr[i] = *(const bf16x8*)(Bf + i * 16 * 32);
    }
#pragma unroll
    for (int i = 0; i < 4; ++i)
#pragma unroll
      for (int j = 0; j < 4; ++j)
        acc[i][j] = __builtin_amdgcn_mfma_f32_16x16x32_bf16(af[i], bfr[j], acc[i][j], 0, 0, 0);
    __syncthreads();
  }

  const int r0 = m0 + wm * 64 + ((l >> 4) << 2);
  const int c0c = n0 + wn * 64 + (l & 15);
#pragma unroll
  for (int j = 0; j < 4; ++j) {
    const int col = c0c + j * 16;
    const float b = bias[col];
#pragma unroll
    for (int i = 0; i < 4; ++i)
#pragma unroll
      for (int r = 0; r < 4; ++r) {
        float v = acc[i][j][r] + b;
        if (relu) v = fmaxf(v, 0.0f);
        C[(size_t)(r0 + i * 16 + r) * N + col] = f2bf(v);
      }
  }
}

// ---------- split-K GEMM2: Ep[split][8192][128] fp32 partials, N=128 fixed ----------
__global__ __launch_bounds__(256) void k_gemm_sk(const u16* __restrict__ A, const u16* __restrict__ Bt,
                                                 float* __restrict__ Ep, int K, int Ksplit) {
  __shared__ __align__(16) u16 As[128 * 32];
  __shared__ __align__(16) u16 Bs[128 * 32];
  const int tid = threadIdx.x;
  const int l = tid & 63, w = tid >> 6;
  const int wm = w >> 1, wn = w & 1;
  const int m0 = blockIdx.y * 128;
  const int split = blockIdx.x;
  const int k0s = split * Ksplit;

  const int rs = w * 16 + (l >> 2);
  const int kb = (l & 3) * 16;
  const char* gA0 = (const char*)(A + (size_t)(m0 + rs) * K) + kb;
  const char* gA1 = gA0 + (size_t)64 * K * 2;
  const char* gB0 = (const char*)(Bt + (size_t)rs * K) + kb;
  const char* gB1 = gB0 + (size_t)64 * K * 2;
  char* lA0 = (char*)As + w * 1024 + l * 16;
  char* lA1 = lA0 + 4096;
  char* lB0 = (char*)Bs + w * 1024 + l * 16;
  char* lB1 = lB0 + 4096;

  const u16* Af = As + (wm * 64 + (l & 15)) * 32 + (l >> 4) * 8;
  const u16* Bf = Bs + (wn * 64 + (l & 15)) * 32 + (l >> 4) * 8;

  f32x4 acc[4][4] = {};

  for (int k0 = k0s; k0 < k0s + Ksplit; k0 += 32) {
    const int kc = k0 * 2;
    g2l16(gA0 + kc, lA0);
    g2l16(gA1 + kc, lA1);
    g2l16(gB0 + kc, lB0);
    g2l16(gB1 + kc, lB1);
    asm volatile("s_waitcnt vmcnt(0)" ::: "memory");
    __syncthreads();
    bf16x8 af[4], bfr[4];
#pragma unroll
    for (int i = 0; i < 4; ++i) {
      af[i] = *(const bf16x8*)(Af + i * 16 * 32);
      bfr[i] = *(const bf16x8*)(Bf + i * 16 * 32);
    }
#pragma unroll
    for (int i = 0; i < 4; ++i)
#pragma unroll
      for (int j = 0; j < 4; ++j)
        acc[i][j] = __builtin_amdgcn_mfma_f32_16x16x32_bf16(af[i], bfr[j], acc[i][j], 0, 0, 0);
    __syncthreads();
  }

  const int r0 = m0 + wm * 64 + ((l >> 4) << 2);
  const int c0c = wn * 64 + (l & 15);
#pragma unroll
  for (int j = 0; j < 4; ++j) {
    const int col = c0c + j * 16;
#pragma unroll
    for (int i = 0; i < 4; ++i)
#pragma unroll
      for (int r = 0; r < 4; ++r)
        Ep[((size_t)split * 8192 + r0 + i * 16 + r) * 128 + col] = acc[i][j][r];
  }
}

// ---------- sum split-K partials + bias, L2-normalize rows, write bf16 f ----------
__global__ __launch_bounds__(256) void k_norm(const float* __restrict__ Ep,
                                              const float* __restrict__ b2, u16* __restrict__ F) {
  const int l = threadIdx.x & 63, w = threadIdx.x >> 6;
  const int row = blockIdx.x * 4 + w;
  const float2* base = (const float2*)Ep + (size_t)row * 64 + l;
  float x = 0.f, y = 0.f;
#pragma unroll
  for (int s = 0; s < 4; ++s) {
    float2 t = base[(size_t)s * (8192 * 64)];
    x += t.x; y += t.y;
  }
  x += b2[l * 2]; y += b2[l * 2 + 1];
  float sq = x * x + y * y;
#pragma unroll
  for (int off = 1; off < 64; off <<= 1) sq += __shfl_xor(sq, off);
  const float inv = 1.0f / sqrtf(sq);
  F[(size_t)row * 128 + l * 2] = f2bf(x * inv);
  F[(size_t)row * 128 + l * 2 + 1] = f2bf(y * inv);
}

// ---------- fused sim GEMM + fixed-max sumexp partials ----------
// grid (4 col-chunks of 2048, 128 row-tiles of 64). Sp[chunk][8192] = sum_j exp(sim/T - INVT), diag excluded
__global__ __launch_bounds__(256) void k_sim(const u16* __restrict__ F, float* __restrict__ Sp) {
  __shared__ __align__(16) u16 As[64 * 128];  // 16 KB: this block's 64 f-rows
  const int tid = threadIdx.x;
  const int l = tid & 63, w = tid >> 6;
  const int wm = w >> 1, wn = w & 1;
  const int row0 = blockIdx.y * 64;
  const int chunk = blockIdx.x;

#pragma unroll
  for (int j = 0; j < 4; ++j) {
    const int c = j * 4 + w;
    const int r = c * 4 + (l >> 4);
    const int cb = (l & 15) * 16;
    g2l16((const char*)(F + (size_t)(row0 + r) * 128) + cb, (char*)As + c * 1024 + l * 16);
  }
  asm volatile("s_waitcnt vmcnt(0)" ::: "memory");
  __syncthreads();

  bf16x8 af[2][4];
#pragma unroll
  for (int i = 0; i < 2; ++i)
#pragma unroll
    for (int s = 0; s < 4; ++s)
      af[i][s] = *(const bf16x8*)(As + (wm * 32 + i * 16 + (l & 15)) * 128 + s * 32 + (l >> 4) * 8);

  float runS[2][4] = {};
#pragma unroll 1
  for (int ct = 0; ct < 16; ++ct) {
    const int n0 = chunk * 2048 + ct * 128 + wn * 64;
    f32x4 acc[2][4] = {};
#pragma unroll
    for (int j = 0; j < 4; ++j) {
      const u16* bp = F + (size_t)(n0 + j * 16 + (l & 15)) * 128 + (l >> 4) * 8;
#pragma unroll
      for (int s = 0; s < 4; ++s) {
        bf16x8 bfr = *(const bf16x8*)(bp + s * 32);
        acc[0][j] = __builtin_amdgcn_mfma_f32_16x16x32_bf16(af[0][s], bfr, acc[0][j], 0, 0, 0);
        acc[1][j] = __builtin_amdgcn_mfma_f32_16x16x32_bf16(af[1][s], bfr, acc[1][j], 0, 0, 0);
      }
    }
#pragma unroll
    for (int i = 0; i < 2; ++i) {
      const int rb = row0 + wm * 32 + i * 16 + ((l >> 4) << 2);
#pragma unroll
      for (int r = 0; r < 4; ++r) {
        const int grow = rb + r;
        float sp = 0.f;
#pragma unroll
        for (int j = 0; j < 4; ++j) {
          const int gcol = n0 + j * 16 + (l & 15);
          float v = acc[i][j][r] * INVT;
          v = (gcol == grow) ? -1e30f : v;  // exclude self-similarity
          sp += __expf(v - INVT);
        }
        sp += __shfl_xor(sp, 1);
        sp += __shfl_xor(sp, 2);
        sp += __shfl_xor(sp, 4);
        sp += __shfl_xor(sp, 8);
        runS[i][r] += sp;
      }
    }
  }

  __syncthreads();
  float* red = (float*)As;  // reuse LDS: 64 floats
  if (wn == 0 && (l & 15) == 0) {
#pragma unroll
    for (int i = 0; i < 2; ++i)
#pragma unroll
      for (int r = 0; r < 4; ++r)
        red[wm * 32 + i * 16 + ((l >> 4) << 2) + r] = runS[i][r];
  }
  __syncthreads();
  if (wn == 1 && (l & 15) == 0) {
#pragma unroll
    for (int i = 0; i < 2; ++i)
#pragma unroll
      for (int r = 0; r < 4; ++r) {
        const int rr = wm * 32 + i * 16 + ((l >> 4) << 2) + r;
        Sp[(size_t)chunk * 8192 + row0 + rr] = red[rr] + runS[i][r];
      }
  }
}

// ---------- merge chunk partials, compute pos, reduce mean(lse - pos) ----------
__global__ __launch_bounds__(256) void k_combine(const float* __restrict__ Sp,
                                                 const u16* __restrict__ F,
                                                 float* __restrict__ out) {
  const int r = blockIdx.x * 256 + threadIdx.x;
  float S = Sp[r] + Sp[8192 + r] + Sp[2 * 8192 + r] + Sp[3 * 8192 + r];
  const float lse = INVT + logf(S);
  const int par = (r + 4096) & 8191;
  const u16* a = F + (size_t)r * 128;
  const u16* b = F + (size_t)par * 128;
  float dot = 0.f;
#pragma unroll 8
  for (int k = 0; k < 128; ++k) dot = fmaf(bf2f(a[k]), bf2f(b[k]), dot);
  float contrib = lse - dot * INVT;
#pragma unroll
  for (int off = 1; off < 64; off <<= 1) contrib += __shfl_xor(contrib, off);
  if ((threadIdx.x & 63) == 0) atomicAdd(out, contrib * (1.0f / 8192.0f));
}

extern "C" void kernel_launch(void* const* d_in, const int* in_sizes, int n_in,
                              void* d_out, int out_size, void* d_ws, size_t ws_size,
                              hipStream_t stream) {
  const float* input1 = (const float*)d_in[0];
  const float* input2 = (const float*)d_in[1];
  const float* W0 = (const float*)d_in[2];
  const float* b0 = (const float*)d_in[3];
  const float* W1 = (const float*)d_in[4];
  const float* b1 = (const float*)d_in[5];
  const float* W2 = (const float*)d_in[6];
  const float* b2 = (const float*)d_in[7];
  float* out = (float*)d_out;
  char* ws = (char*)d_ws;

  // workspace layout (bytes): total 86,638,592
  u16* Xb = (u16*)(ws + 0);              // [8192][2048] bf16 (33.5 MB); reused as H2
  u16* H1 = (u16*)(ws + 33554432);       // [8192][2048] bf16
  u16* W0T = (u16*)(ws + 67108864);      // [2048][2048] bf16
  u16* W1T = (u16*)(ws + 75497472);      // [2048][2048] bf16
  float* Ep = (float*)(ws + 67108864);   // [4][8192][128] fp32, overlays dead W0T/W1T
  u16* W2T = (u16*)(ws + 83886080);      // [128][2048] bf16
  u16* Ff = (u16*)(ws + 84410368);       // [8192][128] bf16 normalized embeddings
  float* Sp = (float*)(ws + 86507520);   // [4][8192] fp32 sumexp partials
  u16* H2 = Xb;

  hipMemsetAsync(d_out, 0, sizeof(float), stream);
  k_cvt<<<8192, 256, 0, stream>>>(input1, Xb, 8388608);
  k_cvt<<<8192, 256, 0, stream>>>(input2, Xb + 8388608, 8388608);
  k_transpose<<<dim3(32, 32), 256, 0, stream>>>(W0, W0T, 2048, 2048);
  k_transpose<<<dim3(32, 32), 256, 0, stream>>>(W1, W1T, 2048, 2048);
  k_transpose<<<dim3(2, 32), 256, 0, stream>>>(W2, W2T, 2048, 128);
  k_gemm<<<dim3(16, 64), 256, 0, stream>>>(Xb, W0T, b0, H1, 8192, 2048, 2048, 1);
  k_gemm<<<dim3(16, 64), 256, 0, stream>>>(H1, W1T, b1, H2, 8192, 2048, 2048, 0);
  k_gemm_sk<<<dim3(4, 64), 256, 0, stream>>>(H2, W2T, Ep, 2048, 512);
  k_norm<<<2048, 256, 0, stream>>>(Ep, b2, Ff);
  k_sim<<<dim3(4, 128), 256, 0, stream>>>(Ff, Sp);
  k_combine<<<32, 256, 0, stream>>>(Sp, Ff, out);
}

// Round 2
// 422.765 us; speedup vs baseline: 1.0656x; 1.0656x over previous
//
#include <hip/hip_runtime.h>
#include <stdint.h>

typedef float f32x4 __attribute__((ext_vector_type(4)));
typedef float f32x16 __attribute__((ext_vector_type(16)));
typedef __bf16 bf16x8 __attribute__((ext_vector_type(8)));
typedef unsigned short u16;
typedef unsigned int u32;

#define INVT 14.285714285714286f   // 1/0.07 ; also the fixed LSE max bound (cos<=1)

__device__ __forceinline__ u16 f2bf(float f) {
  u32 u = __float_as_uint(f);
  u32 r = (u + 0x7fffu + ((u >> 16) & 1u)) >> 16;
  return (u16)r;
}
__device__ __forceinline__ float bf2f(u16 h) { return __uint_as_float(((u32)h) << 16); }

// async global->LDS, 16B per lane (lane i lands at base + i*16)
__device__ __forceinline__ void g2l16(const void* g, void* l) {
  auto gp = reinterpret_cast<__attribute__((address_space(1))) uint32_t*>(
      reinterpret_cast<uintptr_t>(g));
  auto lp = reinterpret_cast<__attribute__((address_space(3))) uint32_t*>(
      reinterpret_cast<uintptr_t>(l));
  __builtin_amdgcn_global_load_lds(gp, lp, 16, 0, 0);
}

// ---------- fp32 -> bf16 elementwise convert ----------
__global__ __launch_bounds__(256) void k_cvt(const float* __restrict__ in,
                                             u16* __restrict__ out, int n) {
  int i = (blockIdx.x * 256 + threadIdx.x) * 4;
  if (i >= n) return;
  float4 v = *(const float4*)(in + i);
  ushort4 p;
  p.x = f2bf(v.x); p.y = f2bf(v.y); p.z = f2bf(v.z); p.w = f2bf(v.w);
  *(ushort4*)(out + i) = p;
}

// ---------- fp32 [R][C] -> bf16 [C][R] transpose ----------
__global__ __launch_bounds__(256) void k_transpose(const float* __restrict__ in,
                                                   u16* __restrict__ out, int R, int C) {
  __shared__ float t[64][65];
  const int r0 = blockIdx.y * 64, c0 = blockIdx.x * 64;
#pragma unroll
  for (int p = 0; p < 16; ++p) {
    int idx = p * 256 + threadIdx.x;
    int r = idx >> 6, c = idx & 63;
    t[r][c] = in[(size_t)(r0 + r) * C + (c0 + c)];
  }
  __syncthreads();
#pragma unroll
  for (int p = 0; p < 16; ++p) {
    int idx = p * 256 + threadIdx.x;
    int c = idx >> 6, r = idx & 63;
    out[(size_t)(c0 + c) * R + (r0 + r)] = f2bf(t[r][c]);
  }
}

// ---------- bf16 GEMM: C[M][N] = op(A[M][K] @ Bt[N][K]^T + bias), optional relu ----------
// 128x128 tile, BK=32, 4 waves as 2x2, each wave 64x64 via 2x2 of 32x32x16 MFMA.
// LDS tile is XOR-swizzled: physical 16B chunk p of row r holds logical chunk p ^ ((r>>1)&3)
// -> ds_read_b128 frag reads touch all 8 bank-quads evenly (conflict-free).
__global__ __launch_bounds__(256) void k_gemm(const u16* __restrict__ A, const u16* __restrict__ Bt,
                                              const float* __restrict__ bias, u16* __restrict__ C,
                                              int M, int N, int K, int relu) {
  __shared__ __align__(16) u16 As[128 * 32];
  __shared__ __align__(16) u16 Bs[128 * 32];
  const int tid = threadIdx.x;
  const int l = tid & 63, w = tid >> 6;
  const int wm = w >> 1, wn = w & 1;
  const int m0 = blockIdx.y * 128, n0 = blockIdx.x * 128;

  // staging: wave w covers rows w*16..w*16+15 (and +64); lane l -> row rs, phys chunk l&3
  const int rs = w * 16 + (l >> 2);
  const int kb = ((l & 3) ^ ((rs >> 1) & 3)) * 16;  // swizzled logical k-chunk (bytes)
  const char* gA0 = (const char*)(A + (size_t)(m0 + rs) * K) + kb;
  const char* gA1 = gA0 + (size_t)64 * K * 2;
  const char* gB0 = (const char*)(Bt + (size_t)(n0 + rs) * K) + kb;
  const char* gB1 = gB0 + (size_t)64 * K * 2;
  char* lA0 = (char*)As + w * 1024 + l * 16;
  char* lA1 = lA0 + 4096;
  char* lB0 = (char*)Bs + w * 1024 + l * 16;
  char* lB1 = lB0 + 4096;

  // frag read: A[m=lane&31][k=(lane>>5)*8+j]; s(r) is fm/64-row invariant
  const int rA = wm * 64 + (l & 31);
  const int rB = wn * 64 + (l & 31);
  const int c0 = l >> 5;
  const int sA = (rA >> 1) & 3;
  const int sB = (rB >> 1) & 3;

  f32x16 acc[2][2] = {};

  for (int k0 = 0; k0 < K; k0 += 32) {
    const int kc = k0 * 2;
    g2l16(gA0 + kc, lA0);
    g2l16(gA1 + kc, lA1);
    g2l16(gB0 + kc, lB0);
    g2l16(gB1 + kc, lB1);
    asm volatile("s_waitcnt vmcnt(0)" ::: "memory");
    __syncthreads();
    bf16x8 af[2][2], bfr[2][2];
#pragma unroll
    for (int t = 0; t < 2; ++t) {
      const int ca = (((t << 1) + c0) ^ sA) * 8;
      const int cb2 = (((t << 1) + c0) ^ sB) * 8;
#pragma unroll
      for (int fm = 0; fm < 2; ++fm)
        af[t][fm] = *(const bf16x8*)(As + (rA + fm * 32) * 32 + ca);
#pragma unroll
      for (int fn = 0; fn < 2; ++fn)
        bfr[t][fn] = *(const bf16x8*)(Bs + (rB + fn * 32) * 32 + cb2);
    }
#pragma unroll
    for (int t = 0; t < 2; ++t)
#pragma unroll
      for (int fm = 0; fm < 2; ++fm)
#pragma unroll
        for (int fn = 0; fn < 2; ++fn)
          acc[fm][fn] = __builtin_amdgcn_mfma_f32_32x32x16_bf16(af[t][fm], bfr[t][fn],
                                                                acc[fm][fn], 0, 0, 0);
    __syncthreads();
  }

  // C/D: col = lane&31, row = (reg&3) + 8*(reg>>2) + 4*(lane>>5)
  const int colb = n0 + wn * 64 + (l & 31);
  const int rowb = m0 + wm * 64 + 4 * (l >> 5);
#pragma unroll
  for (int fn = 0; fn < 2; ++fn) {
    const float b = bias[colb + fn * 32];
#pragma unroll
    for (int fm = 0; fm < 2; ++fm)
#pragma unroll
      for (int g = 0; g < 4; ++g)
#pragma unroll
        for (int rr = 0; rr < 4; ++rr) {
          float v = acc[fm][fn][g * 4 + rr] + b;
          if (relu) v = fmaxf(v, 0.0f);
          C[(size_t)(rowb + fm * 32 + g * 8 + rr) * N + colb + fn * 32] = f2bf(v);
        }
  }
}

// ---------- split-K GEMM2: Ep[split][8192][128] fp32 partials, N=128 fixed ----------
__global__ __launch_bounds__(256) void k_gemm_sk(const u16* __restrict__ A, const u16* __restrict__ Bt,
                                                 float* __restrict__ Ep, int K, int Ksplit) {
  __shared__ __align__(16) u16 As[128 * 32];
  __shared__ __align__(16) u16 Bs[128 * 32];
  const int tid = threadIdx.x;
  const int l = tid & 63, w = tid >> 6;
  const int wm = w >> 1, wn = w & 1;
  const int m0 = blockIdx.y * 128;
  const int split = blockIdx.x;
  const int k0s = split * Ksplit;

  const int rs = w * 16 + (l >> 2);
  const int kb = ((l & 3) ^ ((rs >> 1) & 3)) * 16;
  const char* gA0 = (const char*)(A + (size_t)(m0 + rs) * K) + kb;
  const char* gA1 = gA0 + (size_t)64 * K * 2;
  const char* gB0 = (const char*)(Bt + (size_t)rs * K) + kb;
  const char* gB1 = gB0 + (size_t)64 * K * 2;
  char* lA0 = (char*)As + w * 1024 + l * 16;
  char* lA1 = lA0 + 4096;
  char* lB0 = (char*)Bs + w * 1024 + l * 16;
  char* lB1 = lB0 + 4096;

  const int rA = wm * 64 + (l & 31);
  const int rB = wn * 64 + (l & 31);
  const int c0 = l >> 5;
  const int sA = (rA >> 1) & 3;
  const int sB = (rB >> 1) & 3;

  f32x16 acc[2][2] = {};

  for (int k0 = k0s; k0 < k0s + Ksplit; k0 += 32) {
    const int kc = k0 * 2;
    g2l16(gA0 + kc, lA0);
    g2l16(gA1 + kc, lA1);
    g2l16(gB0 + kc, lB0);
    g2l16(gB1 + kc, lB1);
    asm volatile("s_waitcnt vmcnt(0)" ::: "memory");
    __syncthreads();
    bf16x8 af[2][2], bfr[2][2];
#pragma unroll
    for (int t = 0; t < 2; ++t) {
      const int ca = (((t << 1) + c0) ^ sA) * 8;
      const int cb2 = (((t << 1) + c0) ^ sB) * 8;
#pragma unroll
      for (int fm = 0; fm < 2; ++fm)
        af[t][fm] = *(const bf16x8*)(As + (rA + fm * 32) * 32 + ca);
#pragma unroll
      for (int fn = 0; fn < 2; ++fn)
        bfr[t][fn] = *(const bf16x8*)(Bs + (rB + fn * 32) * 32 + cb2);
    }
#pragma unroll
    for (int t = 0; t < 2; ++t)
#pragma unroll
      for (int fm = 0; fm < 2; ++fm)
#pragma unroll
        for (int fn = 0; fn < 2; ++fn)
          acc[fm][fn] = __builtin_amdgcn_mfma_f32_32x32x16_bf16(af[t][fm], bfr[t][fn],
                                                                acc[fm][fn], 0, 0, 0);
    __syncthreads();
  }

  const int colb = wn * 64 + (l & 31);
  const int rowb = wm * 64 + 4 * (l >> 5);
#pragma unroll
  for (int fn = 0; fn < 2; ++fn)
#pragma unroll
    for (int fm = 0; fm < 2; ++fm)
#pragma unroll
      for (int g = 0; g < 4; ++g)
#pragma unroll
        for (int rr = 0; rr < 4; ++rr)
          Ep[((size_t)split * 8192 + m0 + rowb + fm * 32 + g * 8 + rr) * 128 + colb + fn * 32] =
              acc[fm][fn][g * 4 + rr];
}

// ---------- sum split-K partials + bias, L2-normalize rows, write bf16 f ----------
__global__ __launch_bounds__(256) void k_norm(const float* __restrict__ Ep,
                                              const float* __restrict__ b2, u16* __restrict__ F) {
  const int l = threadIdx.x & 63, w = threadIdx.x >> 6;
  const int row = blockIdx.x * 4 + w;
  const float2* base = (const float2*)Ep + (size_t)row * 64 + l;
  float x = 0.f, y = 0.f;
#pragma unroll
  for (int s = 0; s < 4; ++s) {
    float2 t = base[(size_t)s * (8192 * 64)];
    x += t.x; y += t.y;
  }
  x += b2[l * 2]; y += b2[l * 2 + 1];
  float sq = x * x + y * y;
#pragma unroll
  for (int off = 1; off < 64; off <<= 1) sq += __shfl_xor(sq, off);
  const float inv = 1.0f / sqrtf(sq);
  F[(size_t)row * 128 + l * 2] = f2bf(x * inv);
  F[(size_t)row * 128 + l * 2 + 1] = f2bf(y * inv);
}

// ---------- fused sim GEMM + fixed-max sumexp partials ----------
// grid (4 col-chunks of 2048, 128 row-tiles of 64). Sp[chunk][8192] = sum_j exp(sim/T - INVT), diag excluded
__global__ __launch_bounds__(256) void k_sim(const u16* __restrict__ F, float* __restrict__ Sp) {
  __shared__ __align__(16) u16 As[64 * 128];  // 16 KB: this block's 64 f-rows
  const int tid = threadIdx.x;
  const int l = tid & 63, w = tid >> 6;
  const int wm = w >> 1, wn = w & 1;
  const int row0 = blockIdx.y * 64;
  const int chunk = blockIdx.x;

#pragma unroll
  for (int j = 0; j < 4; ++j) {
    const int c = j * 4 + w;
    const int r = c * 4 + (l >> 4);
    const int cb = (l & 15) * 16;
    g2l16((const char*)(F + (size_t)(row0 + r) * 128) + cb, (char*)As + c * 1024 + l * 16);
  }
  asm volatile("s_waitcnt vmcnt(0)" ::: "memory");
  __syncthreads();

  bf16x8 af[2][4];
#pragma unroll
  for (int i = 0; i < 2; ++i)
#pragma unroll
    for (int s = 0; s < 4; ++s)
      af[i][s] = *(const bf16x8*)(As + (wm * 32 + i * 16 + (l & 15)) * 128 + s * 32 + (l >> 4) * 8);

  float runS[2][4] = {};
#pragma unroll 1
  for (int ct = 0; ct < 16; ++ct) {
    const int n0 = chunk * 2048 + ct * 128 + wn * 64;
    f32x4 acc[2][4] = {};
#pragma unroll
    for (int j = 0; j < 4; ++j) {
      const u16* bp = F + (size_t)(n0 + j * 16 + (l & 15)) * 128 + (l >> 4) * 8;
#pragma unroll
      for (int s = 0; s < 4; ++s) {
        bf16x8 bfr = *(const bf16x8*)(bp + s * 32);
        acc[0][j] = __builtin_amdgcn_mfma_f32_16x16x32_bf16(af[0][s], bfr, acc[0][j], 0, 0, 0);
        acc[1][j] = __builtin_amdgcn_mfma_f32_16x16x32_bf16(af[1][s], bfr, acc[1][j], 0, 0, 0);
      }
    }
#pragma unroll
    for (int i = 0; i < 2; ++i) {
      const int rb = row0 + wm * 32 + i * 16 + ((l >> 4) << 2);
#pragma unroll
      for (int r = 0; r < 4; ++r) {
        const int grow = rb + r;
        float sp = 0.f;
#pragma unroll
        for (int j = 0; j < 4; ++j) {
          const int gcol = n0 + j * 16 + (l & 15);
          float v = acc[i][j][r] * INVT;
          v = (gcol == grow) ? -1e30f : v;  // exclude self-similarity
          sp += __expf(v - INVT);
        }
        sp += __shfl_xor(sp, 1);
        sp += __shfl_xor(sp, 2);
        sp += __shfl_xor(sp, 4);
        sp += __shfl_xor(sp, 8);
        runS[i][r] += sp;
      }
    }
  }

  __syncthreads();
  float* red = (float*)As;  // reuse LDS: 64 floats
  if (wn == 0 && (l & 15) == 0) {
#pragma unroll
    for (int i = 0; i < 2; ++i)
#pragma unroll
      for (int r = 0; r < 4; ++r)
        red[wm * 32 + i * 16 + ((l >> 4) << 2) + r] = runS[i][r];
  }
  __syncthreads();
  if (wn == 1 && (l & 15) == 0) {
#pragma unroll
    for (int i = 0; i < 2; ++i)
#pragma unroll
      for (int r = 0; r < 4; ++r) {
        const int rr = wm * 32 + i * 16 + ((l >> 4) << 2) + r;
        Sp[(size_t)chunk * 8192 + row0 + rr] = red[rr] + runS[i][r];
      }
  }
}

// ---------- merge chunk partials, compute pos, reduce mean(lse - pos) ----------
__global__ __launch_bounds__(256) void k_combine(const float* __restrict__ Sp,
                                                 const u16* __restrict__ F,
                                                 float* __restrict__ out) {
  const int r = blockIdx.x * 256 + threadIdx.x;
  float S = Sp[r] + Sp[8192 + r] + Sp[2 * 8192 + r] + Sp[3 * 8192 + r];
  const float lse = INVT + logf(S);
  const int par = (r + 4096) & 8191;
  const u16* a = F + (size_t)r * 128;
  const u16* b = F + (size_t)par * 128;
  float dot = 0.f;
#pragma unroll 8
  for (int k = 0; k < 128; ++k) dot = fmaf(bf2f(a[k]), bf2f(b[k]), dot);
  float contrib = lse - dot * INVT;
#pragma unroll
  for (int off = 1; off < 64; off <<= 1) contrib += __shfl_xor(contrib, off);
  if ((threadIdx.x & 63) == 0) atomicAdd(out, contrib * (1.0f / 8192.0f));
}

extern "C" void kernel_launch(void* const* d_in, const int* in_sizes, int n_in,
                              void* d_out, int out_size, void* d_ws, size_t ws_size,
                              hipStream_t stream) {
  const float* input1 = (const float*)d_in[0];
  const float* input2 = (const float*)d_in[1];
  const float* W0 = (const float*)d_in[2];
  const float* b0 = (const float*)d_in[3];
  const float* W1 = (const float*)d_in[4];
  const float* b1 = (const float*)d_in[5];
  const float* W2 = (const float*)d_in[6];
  const float* b2 = (const float*)d_in[7];
  float* out = (float*)d_out;
  char* ws = (char*)d_ws;

  // workspace layout (bytes): total 86,638,592
  u16* Xb = (u16*)(ws + 0);              // [8192][2048] bf16 (33.5 MB); reused as H2
  u16* H1 = (u16*)(ws + 33554432);       // [8192][2048] bf16
  u16* W0T = (u16*)(ws + 67108864);      // [2048][2048] bf16
  u16* W1T = (u16*)(ws + 75497472);      // [2048][2048] bf16
  float* Ep = (float*)(ws + 67108864);   // [4][8192][128] fp32, overlays dead W0T/W1T
  u16* W2T = (u16*)(ws + 83886080);      // [128][2048] bf16
  u16* Ff = (u16*)(ws + 84410368);       // [8192][128] bf16 normalized embeddings
  float* Sp = (float*)(ws + 86507520);   // [4][8192] fp32 sumexp partials
  u16* H2 = Xb;

  hipMemsetAsync(d_out, 0, sizeof(float), stream);
  k_cvt<<<8192, 256, 0, stream>>>(input1, Xb, 8388608);
  k_cvt<<<8192, 256, 0, stream>>>(input2, Xb + 8388608, 8388608);
  k_transpose<<<dim3(32, 32), 256, 0, stream>>>(W0, W0T, 2048, 2048);
  k_transpose<<<dim3(32, 32), 256, 0, stream>>>(W1, W1T, 2048, 2048);
  k_transpose<<<dim3(2, 32), 256, 0, stream>>>(W2, W2T, 2048, 128);
  k_gemm<<<dim3(16, 64), 256, 0, stream>>>(Xb, W0T, b0, H1, 8192, 2048, 2048, 1);
  k_gemm<<<dim3(16, 64), 256, 0, stream>>>(H1, W1T, b1, H2, 8192, 2048, 2048, 0);
  k_gemm_sk<<<dim3(4, 64), 256, 0, stream>>>(H2, W2T, Ep, 2048, 512);
  k_norm<<<2048, 256, 0, stream>>>(Ep, b2, Ff);
  k_sim<<<dim3(4, 128), 256, 0, stream>>>(Ff, Sp);
  k_combine<<<32, 256, 0, stream>>>(Sp, Ff, out);
}

// Round 3
// 403.380 us; speedup vs baseline: 1.1168x; 1.0481x over previous
//
#include <hip/hip_runtime.h>
#include <stdint.h>

typedef float f32x4 __attribute__((ext_vector_type(4)));
typedef float f32x16 __attribute__((ext_vector_type(16)));
typedef __bf16 bf16x8 __attribute__((ext_vector_type(8)));
typedef unsigned short u16;
typedef unsigned int u32;

#define INVT 14.285714285714286f   // 1/0.07 ; also the fixed LSE max bound (cos<=1)

__device__ __forceinline__ u16 f2bf(float f) {
  u32 u = __float_as_uint(f);
  u32 r = (u + 0x7fffu + ((u >> 16) & 1u)) >> 16;
  return (u16)r;
}
__device__ __forceinline__ float bf2f(u16 h) { return __uint_as_float(((u32)h) << 16); }

// async global->LDS, 16B per lane (lane i lands at base + i*16)
__device__ __forceinline__ void g2l16(const void* g, void* l) {
  auto gp = reinterpret_cast<__attribute__((address_space(1))) uint32_t*>(
      reinterpret_cast<uintptr_t>(g));
  auto lp = reinterpret_cast<__attribute__((address_space(3))) uint32_t*>(
      reinterpret_cast<uintptr_t>(l));
  __builtin_amdgcn_global_load_lds(gp, lp, 16, 0, 0);
}

// ---------- fp32 -> bf16 convert, both inputs in one launch ----------
__global__ __launch_bounds__(256) void k_cvt2(const float* __restrict__ in1,
                                              const float* __restrict__ in2,
                                              u16* __restrict__ out) {
  int i = (blockIdx.x * 256 + threadIdx.x) * 4;
  float4 v;
  if (i < 8388608) v = *(const float4*)(in1 + i);
  else             v = *(const float4*)(in2 + (i - 8388608));
  ushort4 p;
  p.x = f2bf(v.x); p.y = f2bf(v.y); p.z = f2bf(v.z); p.w = f2bf(v.w);
  *(ushort4*)(out + i) = p;
}

// ---------- fp32 [R][C] -> bf16 [C][R] transpose (z selects W0/W1) ----------
__global__ __launch_bounds__(256) void k_transpose2(const float* __restrict__ w0,
                                                    u16* __restrict__ w0t,
                                                    const float* __restrict__ w1,
                                                    u16* __restrict__ w1t) {
  const float* in = blockIdx.z ? w1 : w0;
  u16* out = blockIdx.z ? w1t : w0t;
  const int R = 2048, C = 2048;
  __shared__ float t[64][65];
  const int r0 = blockIdx.y * 64, c0 = blockIdx.x * 64;
#pragma unroll
  for (int p = 0; p < 16; ++p) {
    int idx = p * 256 + threadIdx.x;
    int r = idx >> 6, c = idx & 63;
    t[r][c] = in[(size_t)(r0 + r) * C + (c0 + c)];
  }
  __syncthreads();
#pragma unroll
  for (int p = 0; p < 16; ++p) {
    int idx = p * 256 + threadIdx.x;
    int c = idx >> 6, r = idx & 63;
    out[(size_t)(c0 + c) * R + (r0 + r)] = f2bf(t[r][c]);
  }
}

__global__ __launch_bounds__(256) void k_transpose(const float* __restrict__ in,
                                                   u16* __restrict__ out, int R, int C) {
  __shared__ float t[64][65];
  const int r0 = blockIdx.y * 64, c0 = blockIdx.x * 64;
#pragma unroll
  for (int p = 0; p < 16; ++p) {
    int idx = p * 256 + threadIdx.x;
    int r = idx >> 6, c = idx & 63;
    t[r][c] = in[(size_t)(r0 + r) * C + (c0 + c)];
  }
  __syncthreads();
#pragma unroll
  for (int p = 0; p < 16; ++p) {
    int idx = p * 256 + threadIdx.x;
    int c = idx >> 6, r = idx & 63;
    out[(size_t)(c0 + c) * R + (r0 + r)] = f2bf(t[r][c]);
  }
}

// ---------- bf16 GEMM: C = op(A @ Bt^T + bias) ----------
// 128x128 tile, BK=32, DOUBLE-BUFFERED LDS (2x16KB): prefetch tile k+1 while
// computing tile k; steady-state wait is vmcnt(4) (prev tile's 4 loads done,
// next tile's 4 still in flight) + raw s_barrier — never a full drain.
__global__ __launch_bounds__(256, 4) void k_gemm(const u16* __restrict__ A, const u16* __restrict__ Bt,
                                                 const float* __restrict__ bias, u16* __restrict__ C,
                                                 int M, int N, int K, int relu) {
  __shared__ __align__(16) u16 sm[16384];  // [buf][A 4096 u16 | B 4096 u16]
  const int tid = threadIdx.x;
  const int l = tid & 63, w = tid >> 6;
  const int wm = w >> 1, wn = w & 1;

  // XCD-aware swizzle: each XCD (round-robin by flat id, 8 XCDs) owns 2 n-columns
  // -> its B slabs (2 x 512KB) stay L2-resident.
  const int flat = blockIdx.y * gridDim.x + blockIdx.x;
  const int xcd = flat & 7, slot = flat >> 3;
  const int nb = xcd * 2 + (slot >> 6), mb = slot & 63;
  const int m0 = mb * 128, n0 = nb * 128;

  // staging: wave w rows w*16+(l>>2) (+64); phys 16B chunk l&3, xor-swizzled
  const int rs = w * 16 + (l >> 2);
  const int kb = ((l & 3) ^ ((rs >> 1) & 3)) * 16;
  const char* gA = (const char*)(A + (size_t)(m0 + rs) * K) + kb;
  const char* gB = (const char*)(Bt + (size_t)(n0 + rs) * K) + kb;
  const size_t radv = (size_t)64 * K * 2;
  char* lbase = (char*)sm + w * 1024 + l * 16;

  auto issue = [&](int kc, int b) {
    char* d = lbase + b * 16384;
    g2l16(gA + kc, d);
    g2l16(gA + radv + kc, d + 4096);
    g2l16(gB + kc, d + 8192);
    g2l16(gB + radv + kc, d + 12288);
  };

  const int rA = wm * 64 + (l & 31);
  const int rB = wn * 64 + (l & 31);
  const int c0 = l >> 5;
  const int sA = (rA >> 1) & 3, sB = (rB >> 1) & 3;

  f32x16 acc[2][2] = {};

  auto compute = [&](int b) {
    const u16* As = sm + b * 8192;
    const u16* Bs = As + 4096;
    bf16x8 af[2][2], bfr[2][2];
#pragma unroll
    for (int t = 0; t < 2; ++t) {
      const int ca = (((t << 1) + c0) ^ sA) * 8;
      const int cb = (((t << 1) + c0) ^ sB) * 8;
#pragma unroll
      for (int fm = 0; fm < 2; ++fm) af[t][fm] = *(const bf16x8*)(As + (rA + fm * 32) * 32 + ca);
#pragma unroll
      for (int fn = 0; fn < 2; ++fn) bfr[t][fn] = *(const bf16x8*)(Bs + (rB + fn * 32) * 32 + cb);
    }
#pragma unroll
    for (int t = 0; t < 2; ++t)
#pragma unroll
      for (int fm = 0; fm < 2; ++fm)
#pragma unroll
        for (int fn = 0; fn < 2; ++fn)
          acc[fm][fn] = __builtin_amdgcn_mfma_f32_32x32x16_bf16(af[t][fm], bfr[t][fn],
                                                                acc[fm][fn], 0, 0, 0);
  };

#define PHASE(BCUR, BNEXT)                                            \
  {                                                                   \
    if (k + 32 < K) {                                                 \
      issue((k + 32) * 2, BNEXT);                                     \
      asm volatile("s_waitcnt vmcnt(4)\ns_barrier" ::: "memory");     \
    } else {                                                          \
      asm volatile("s_waitcnt vmcnt(0)\ns_barrier" ::: "memory");     \
    }                                                                 \
    compute(BCUR);                                                    \
    asm volatile("s_barrier" ::: "memory");                           \
    k += 32;                                                          \
  }

  issue(0, 0);
  int k = 0;
  do { PHASE(0, 1) PHASE(1, 0) } while (k < K);
#undef PHASE

  // C/D: col = lane&31, row = (reg&3) + 8*(reg>>2) + 4*(lane>>5)
  const int colb = n0 + wn * 64 + (l & 31);
  const int rowb = m0 + wm * 64 + 4 * (l >> 5);
#pragma unroll
  for (int fn = 0; fn < 2; ++fn) {
    const float b = bias[colb + fn * 32];
#pragma unroll
    for (int fm = 0; fm < 2; ++fm)
#pragma unroll
      for (int g = 0; g < 4; ++g)
#pragma unroll
        for (int rr = 0; rr < 4; ++rr) {
          float v = acc[fm][fn][g * 4 + rr] + b;
          if (relu) v = fmaxf(v, 0.0f);
          C[(size_t)(rowb + fm * 32 + g * 8 + rr) * N + colb + fn * 32] = f2bf(v);
        }
  }
}

// ---------- split-K GEMM2 (N=128), same double-buffered loop ----------
__global__ __launch_bounds__(256, 4) void k_gemm_sk(const u16* __restrict__ A, const u16* __restrict__ Bt,
                                                    float* __restrict__ Ep, int K, int Ksplit) {
  __shared__ __align__(16) u16 sm[16384];
  const int tid = threadIdx.x;
  const int l = tid & 63, w = tid >> 6;
  const int wm = w >> 1, wn = w & 1;
  const int m0 = blockIdx.y * 128;
  const int split = blockIdx.x;
  const int k0s = split * Ksplit;

  const int rs = w * 16 + (l >> 2);
  const int kb = ((l & 3) ^ ((rs >> 1) & 3)) * 16;
  const char* gA = (const char*)(A + (size_t)(m0 + rs) * K + k0s) + kb;
  const char* gB = (const char*)(Bt + (size_t)rs * K + k0s) + kb;
  const size_t radv = (size_t)64 * K * 2;
  char* lbase = (char*)sm + w * 1024 + l * 16;

  auto issue = [&](int kc, int b) {
    char* d = lbase + b * 16384;
    g2l16(gA + kc, d);
    g2l16(gA + radv + kc, d + 4096);
    g2l16(gB + kc, d + 8192);
    g2l16(gB + radv + kc, d + 12288);
  };

  const int rA = wm * 64 + (l & 31);
  const int rB = wn * 64 + (l & 31);
  const int c0 = l >> 5;
  const int sA = (rA >> 1) & 3, sB = (rB >> 1) & 3;

  f32x16 acc[2][2] = {};

  auto compute = [&](int b) {
    const u16* As = sm + b * 8192;
    const u16* Bs = As + 4096;
    bf16x8 af[2][2], bfr[2][2];
#pragma unroll
    for (int t = 0; t < 2; ++t) {
      const int ca = (((t << 1) + c0) ^ sA) * 8;
      const int cb = (((t << 1) + c0) ^ sB) * 8;
#pragma unroll
      for (int fm = 0; fm < 2; ++fm) af[t][fm] = *(const bf16x8*)(As + (rA + fm * 32) * 32 + ca);
#pragma unroll
      for (int fn = 0; fn < 2; ++fn) bfr[t][fn] = *(const bf16x8*)(Bs + (rB + fn * 32) * 32 + cb);
    }
#pragma unroll
    for (int t = 0; t < 2; ++t)
#pragma unroll
      for (int fm = 0; fm < 2; ++fm)
#pragma unroll
        for (int fn = 0; fn < 2; ++fn)
          acc[fm][fn] = __builtin_amdgcn_mfma_f32_32x32x16_bf16(af[t][fm], bfr[t][fn],
                                                                acc[fm][fn], 0, 0, 0);
  };

#define PHASE(BCUR, BNEXT)                                            \
  {                                                                   \
    if (k + 32 < Ksplit) {                                            \
      issue((k + 32) * 2, BNEXT);                                     \
      asm volatile("s_waitcnt vmcnt(4)\ns_barrier" ::: "memory");     \
    } else {                                                          \
      asm volatile("s_waitcnt vmcnt(0)\ns_barrier" ::: "memory");     \
    }                                                                 \
    compute(BCUR);                                                    \
    asm volatile("s_barrier" ::: "memory");                           \
    k += 32;                                                          \
  }

  issue(0, 0);
  int k = 0;
  do { PHASE(0, 1) PHASE(1, 0) } while (k < Ksplit);
#undef PHASE

  const int colb = wn * 64 + (l & 31);
  const int rowb = wm * 64 + 4 * (l >> 5);
#pragma unroll
  for (int fn = 0; fn < 2; ++fn)
#pragma unroll
    for (int fm = 0; fm < 2; ++fm)
#pragma unroll
      for (int g = 0; g < 4; ++g)
#pragma unroll
        for (int rr = 0; rr < 4; ++rr)
          Ep[((size_t)split * 8192 + m0 + rowb + fm * 32 + g * 8 + rr) * 128 + colb + fn * 32] =
              acc[fm][fn][g * 4 + rr];
}

// ---------- sum split-K partials + bias, L2-normalize rows, write bf16 f ----------
__global__ __launch_bounds__(256) void k_norm(const float* __restrict__ Ep,
                                              const float* __restrict__ b2, u16* __restrict__ F) {
  const int l = threadIdx.x & 63, w = threadIdx.x >> 6;
  const int row = blockIdx.x * 4 + w;
  const float2* base = (const float2*)Ep + (size_t)row * 64 + l;
  float x = 0.f, y = 0.f;
#pragma unroll
  for (int s = 0; s < 4; ++s) {
    float2 t = base[(size_t)s * (8192 * 64)];
    x += t.x; y += t.y;
  }
  x += b2[l * 2]; y += b2[l * 2 + 1];
  float sq = x * x + y * y;
#pragma unroll
  for (int off = 1; off < 64; off <<= 1) sq += __shfl_xor(sq, off);
  const float inv = 1.0f / sqrtf(sq);
  F[(size_t)row * 128 + l * 2] = f2bf(x * inv);
  F[(size_t)row * 128 + l * 2 + 1] = f2bf(y * inv);
}

// ---------- fused sim GEMM + fixed-max sumexp partials ----------
__global__ __launch_bounds__(256) void k_sim(const u16* __restrict__ F, float* __restrict__ Sp) {
  __shared__ __align__(16) u16 As[64 * 128];
  const int tid = threadIdx.x;
  const int l = tid & 63, w = tid >> 6;
  const int wm = w >> 1, wn = w & 1;
  const int row0 = blockIdx.y * 64;
  const int chunk = blockIdx.x;

#pragma unroll
  for (int j = 0; j < 4; ++j) {
    const int c = j * 4 + w;
    const int r = c * 4 + (l >> 4);
    const int cb = (l & 15) * 16;
    g2l16((const char*)(F + (size_t)(row0 + r) * 128) + cb, (char*)As + c * 1024 + l * 16);
  }
  asm volatile("s_waitcnt vmcnt(0)" ::: "memory");
  __syncthreads();

  bf16x8 af[2][4];
#pragma unroll
  for (int i = 0; i < 2; ++i)
#pragma unroll
    for (int s = 0; s < 4; ++s)
      af[i][s] = *(const bf16x8*)(As + (wm * 32 + i * 16 + (l & 15)) * 128 + s * 32 + (l >> 4) * 8);

  float runS[2][4] = {};
#pragma unroll 1
  for (int ct = 0; ct < 16; ++ct) {
    const int n0 = chunk * 2048 + ct * 128 + wn * 64;
    f32x4 acc[2][4] = {};
#pragma unroll
    for (int j = 0; j < 4; ++j) {
      const u16* bp = F + (size_t)(n0 + j * 16 + (l & 15)) * 128 + (l >> 4) * 8;
#pragma unroll
      for (int s = 0; s < 4; ++s) {
        bf16x8 bfr = *(const bf16x8*)(bp + s * 32);
        acc[0][j] = __builtin_amdgcn_mfma_f32_16x16x32_bf16(af[0][s], bfr, acc[0][j], 0, 0, 0);
        acc[1][j] = __builtin_amdgcn_mfma_f32_16x16x32_bf16(af[1][s], bfr, acc[1][j], 0, 0, 0);
      }
    }
#pragma unroll
    for (int i = 0; i < 2; ++i) {
      const int rb = row0 + wm * 32 + i * 16 + ((l >> 4) << 2);
#pragma unroll
      for (int r = 0; r < 4; ++r) {
        const int grow = rb + r;
        float sp = 0.f;
#pragma unroll
        for (int j = 0; j < 4; ++j) {
          const int gcol = n0 + j * 16 + (l & 15);
          float v = acc[i][j][r] * INVT;
          v = (gcol == grow) ? -1e30f : v;
          sp += __expf(v - INVT);
        }
        sp += __shfl_xor(sp, 1);
        sp += __shfl_xor(sp, 2);
        sp += __shfl_xor(sp, 4);
        sp += __shfl_xor(sp, 8);
        runS[i][r] += sp;
      }
    }
  }

  __syncthreads();
  float* red = (float*)As;
  if (wn == 0 && (l & 15) == 0) {
#pragma unroll
    for (int i = 0; i < 2; ++i)
#pragma unroll
      for (int r = 0; r < 4; ++r)
        red[wm * 32 + i * 16 + ((l >> 4) << 2) + r] = runS[i][r];
  }
  __syncthreads();
  if (wn == 1 && (l & 15) == 0) {
#pragma unroll
    for (int i = 0; i < 2; ++i)
#pragma unroll
      for (int r = 0; r < 4; ++r) {
        const int rr = wm * 32 + i * 16 + ((l >> 4) << 2) + r;
        Sp[(size_t)chunk * 8192 + row0 + rr] = red[rr] + runS[i][r];
      }
  }
}

// ---------- merge chunk partials, compute pos, reduce mean(lse - pos) ----------
__global__ __launch_bounds__(256) void k_combine(const float* __restrict__ Sp,
                                                 const u16* __restrict__ F,
                                                 float* __restrict__ out) {
  const int r = blockIdx.x * 256 + threadIdx.x;
  float S = Sp[r] + Sp[8192 + r] + Sp[2 * 8192 + r] + Sp[3 * 8192 + r];
  const float lse = INVT + logf(S);
  const int par = (r + 4096) & 8191;
  const u16* a = F + (size_t)r * 128;
  const u16* b = F + (size_t)par * 128;
  float dot = 0.f;
#pragma unroll 8
  for (int k = 0; k < 128; ++k) dot = fmaf(bf2f(a[k]), bf2f(b[k]), dot);
  float contrib = lse - dot * INVT;
#pragma unroll
  for (int off = 1; off < 64; off <<= 1) contrib += __shfl_xor(contrib, off);
  if ((threadIdx.x & 63) == 0) atomicAdd(out, contrib * (1.0f / 8192.0f));
}

extern "C" void kernel_launch(void* const* d_in, const int* in_sizes, int n_in,
                              void* d_out, int out_size, void* d_ws, size_t ws_size,
                              hipStream_t stream) {
  const float* input1 = (const float*)d_in[0];
  const float* input2 = (const float*)d_in[1];
  const float* W0 = (const float*)d_in[2];
  const float* b0 = (const float*)d_in[3];
  const float* W1 = (const float*)d_in[4];
  const float* b1 = (const float*)d_in[5];
  const float* W2 = (const float*)d_in[6];
  const float* b2 = (const float*)d_in[7];
  float* out = (float*)d_out;
  char* ws = (char*)d_ws;

  u16* Xb = (u16*)(ws + 0);              // [8192][2048] bf16; reused as H2
  u16* H1 = (u16*)(ws + 33554432);
  u16* W0T = (u16*)(ws + 67108864);
  u16* W1T = (u16*)(ws + 75497472);
  float* Ep = (float*)(ws + 67108864);   // overlays dead W0T/W1T
  u16* W2T = (u16*)(ws + 83886080);
  u16* Ff = (u16*)(ws + 84410368);
  float* Sp = (float*)(ws + 86507520);
  u16* H2 = Xb;

  hipMemsetAsync(d_out, 0, sizeof(float), stream);
  k_cvt2<<<16384, 256, 0, stream>>>(input1, input2, Xb);
  k_transpose2<<<dim3(32, 32, 2), 256, 0, stream>>>(W0, W0T, W1, W1T);
  k_transpose<<<dim3(2, 32), 256, 0, stream>>>(W2, W2T, 2048, 128);
  k_gemm<<<dim3(16, 64), 256, 0, stream>>>(Xb, W0T, b0, H1, 8192, 2048, 2048, 1);
  k_gemm<<<dim3(16, 64), 256, 0, stream>>>(H1, W1T, b1, H2, 8192, 2048, 2048, 0);
  k_gemm_sk<<<dim3(4, 64), 256, 0, stream>>>(H2, W2T, Ep, 2048, 512);
  k_norm<<<2048, 256, 0, stream>>>(Ep, b2, Ff);
  k_sim<<<dim3(4, 128), 256, 0, stream>>>(Ff, Sp);
  k_combine<<<32, 256, 0, stream>>>(Sp, Ff, out);
}

// Round 4
// 374.647 us; speedup vs baseline: 1.2025x; 1.0767x over previous
//
#include <hip/hip_runtime.h>
#include <stdint.h>

typedef float f32x4 __attribute__((ext_vector_type(4)));
typedef float f32x16 __attribute__((ext_vector_type(16)));
typedef __bf16 bf16x8 __attribute__((ext_vector_type(8)));
typedef unsigned short u16;
typedef unsigned int u32;

#define INVT 14.285714285714286f   // 1/0.07 ; also the fixed LSE max bound (cos<=1)

__device__ __forceinline__ u16 f2bf(float f) {
  u32 u = __float_as_uint(f);
  u32 r = (u + 0x7fffu + ((u >> 16) & 1u)) >> 16;
  return (u16)r;
}
__device__ __forceinline__ float bf2f(u16 h) { return __uint_as_float(((u32)h) << 16); }

// async global->LDS, 16B per lane (lane i lands at base + i*16)
__device__ __forceinline__ void g2l16(const void* g, void* l) {
  auto gp = reinterpret_cast<__attribute__((address_space(1))) uint32_t*>(
      reinterpret_cast<uintptr_t>(g));
  auto lp = reinterpret_cast<__attribute__((address_space(3))) uint32_t*>(
      reinterpret_cast<uintptr_t>(l));
  __builtin_amdgcn_global_load_lds(gp, lp, 16, 0, 0);
}

// ---------- fp32 -> bf16 convert, both inputs in one launch ----------
__global__ __launch_bounds__(256) void k_cvt2(const float* __restrict__ in1,
                                              const float* __restrict__ in2,
                                              u16* __restrict__ out) {
  int i = (blockIdx.x * 256 + threadIdx.x) * 4;
  float4 v;
  if (i < 8388608) v = *(const float4*)(in1 + i);
  else             v = *(const float4*)(in2 + (i - 8388608));
  ushort4 p;
  p.x = f2bf(v.x); p.y = f2bf(v.y); p.z = f2bf(v.z); p.w = f2bf(v.w);
  *(ushort4*)(out + i) = p;
}

// ---------- fp32 [R][C] -> bf16 [C][R] transpose (z selects W0/W1) ----------
__global__ __launch_bounds__(256) void k_transpose2(const float* __restrict__ w0,
                                                    u16* __restrict__ w0t,
                                                    const float* __restrict__ w1,
                                                    u16* __restrict__ w1t) {
  const float* in = blockIdx.z ? w1 : w0;
  u16* out = blockIdx.z ? w1t : w0t;
  const int R = 2048, C = 2048;
  __shared__ float t[64][65];
  const int r0 = blockIdx.y * 64, c0 = blockIdx.x * 64;
#pragma unroll
  for (int p = 0; p < 16; ++p) {
    int idx = p * 256 + threadIdx.x;
    int r = idx >> 6, c = idx & 63;
    t[r][c] = in[(size_t)(r0 + r) * C + (c0 + c)];
  }
  __syncthreads();
#pragma unroll
  for (int p = 0; p < 16; ++p) {
    int idx = p * 256 + threadIdx.x;
    int c = idx >> 6, r = idx & 63;
    out[(size_t)(c0 + c) * R + (r0 + r)] = f2bf(t[r][c]);
  }
}

__global__ __launch_bounds__(256) void k_transpose(const float* __restrict__ in,
                                                   u16* __restrict__ out, int R, int C) {
  __shared__ float t[64][65];
  const int r0 = blockIdx.y * 64, c0 = blockIdx.x * 64;
#pragma unroll
  for (int p = 0; p < 16; ++p) {
    int idx = p * 256 + threadIdx.x;
    int r = idx >> 6, c = idx & 63;
    t[r][c] = in[(size_t)(r0 + r) * C + (c0 + c)];
  }
  __syncthreads();
#pragma unroll
  for (int p = 0; p < 16; ++p) {
    int idx = p * 256 + threadIdx.x;
    int c = idx >> 6, r = idx & 63;
    out[(size_t)(c0 + c) * R + (r0 + r)] = f2bf(t[r][c]);
  }
}

// ---------- bf16 GEMM: C = op(A @ Bt^T + bias) ----------
// 256x128 tile, BK=32, 3-STAGE LDS pipeline, ONE barrier per k-step:
//   [wait vmcnt(6)][s_barrier][issue tile k+2][compute tile k]
// Prefetch is 2 phases deep (~>1000 cyc) so the wait is ~free in steady state.
// Write-after-read safe: issue(k+2) targets buf (k+2)%3=(k-1)%3 whose readers
// (compute(k-1)) all passed this phase's barrier. 4 waves, each 128x64 via
// 4x2 of 32x32x16 MFMA -> 16 MFMA per wave per barrier. LDS 72KB -> 2 blk/CU,
// grid 512 = exactly 2/CU co-resident (no tail rounds).
__global__ __launch_bounds__(256, 2) void k_gemm(const u16* __restrict__ A, const u16* __restrict__ Bt,
                                                 const float* __restrict__ bias, u16* __restrict__ C,
                                                 int M, int N, int K, int relu) {
  __shared__ __align__(16) u16 sm[36864];  // 3 stages x (A 256x32 | B 128x32) = 3x24KB
  const int tid = threadIdx.x;
  const int l = tid & 63, w = tid >> 6;
  const int wm = w >> 1, wn = w & 1;
  const int m0 = blockIdx.y * 256, n0 = blockIdx.x * 128;

  // staging: 24 x 1KB chunks/stage (16 A + 8 B), 16 rows per chunk.
  // lane l -> row (l>>2) within chunk, phys 16B piece l&3, xor-swizzled.
  // swizzle s(row)=(row>>1)&3; chunk bases are multiples of 16 rows -> kb is
  // chunk-independent: kb = ((l&3) ^ ((l>>3)&3)) * 16.
  const int kb = ((l & 3) ^ ((l >> 3) & 3)) * 16;
  const char* gA = (const char*)(A + (size_t)(m0 + w * 64 + (l >> 2)) * K) + kb;  // A chunks w*4+j
  const char* gB = (const char*)(Bt + (size_t)(n0 + w * 32 + (l >> 2)) * K) + kb; // B chunks w*2+j
  const size_t chRows = (size_t)16 * K * 2;  // 16-row chunk stride in bytes

  auto issue = [&](int kcB, int stg) {
    char* base = (char*)sm + stg * 24576;
    char* dA = base + (w * 4) * 1024 + l * 16;
    char* dB = base + 16384 + (w * 2) * 1024 + l * 16;
#pragma unroll
    for (int j = 0; j < 4; ++j) g2l16(gA + j * chRows + kcB, dA + j * 1024);
#pragma unroll
    for (int j = 0; j < 2; ++j) g2l16(gB + j * chRows + kcB, dB + j * 1024);
  };

  const int lm = l & 31;           // frag row within 32
  const int c0 = l >> 5;           // k-idx half
  const int sw = (lm >> 1) & 3;    // frag-read swizzle (same for A and B)

  f32x16 acc[4][2] = {};

  auto compute = [&](int stg) {
    const u16* As = sm + stg * 12288;
    const u16* Bs = As + 8192;
#pragma unroll
    for (int t = 0; t < 2; ++t) {
      const int cc = (((t << 1) + c0) ^ sw) * 8;
      bf16x8 a4[4], b2[2];
#pragma unroll
      for (int fm = 0; fm < 4; ++fm)
        a4[fm] = *(const bf16x8*)(As + (wm * 128 + fm * 32 + lm) * 32 + cc);
#pragma unroll
      for (int fn = 0; fn < 2; ++fn)
        b2[fn] = *(const bf16x8*)(Bs + (wn * 64 + fn * 32 + lm) * 32 + cc);
#pragma unroll
      for (int fm = 0; fm < 4; ++fm)
#pragma unroll
        for (int fn = 0; fn < 2; ++fn)
          acc[fm][fn] = __builtin_amdgcn_mfma_f32_32x32x16_bf16(a4[fm], b2[fn],
                                                                acc[fm][fn], 0, 0, 0);
    }
  };

  const int NK = K >> 5;
  issue(0, 0);
  issue(64, 1);
  int st = 0;
  for (int kt = 0; kt < NK; ++kt) {
    if (kt + 1 < NK) asm volatile("s_waitcnt vmcnt(6)" ::: "memory");
    else             asm volatile("s_waitcnt vmcnt(0)" ::: "memory");
    asm volatile("s_barrier" ::: "memory");
    if (kt + 2 < NK) {
      int stp = st + 2; if (stp >= 3) stp -= 3;
      issue((kt + 2) * 64, stp);
    }
    compute(st);
    ++st; if (st == 3) st = 0;
  }

  // C/D 32x32: col = lane&31, row = (reg&3) + 8*(reg>>2) + 4*(lane>>5)
  const int colb = n0 + wn * 64 + lm;
  const int rowb = m0 + wm * 128 + 4 * c0;
#pragma unroll
  for (int fn = 0; fn < 2; ++fn) {
    const float b = bias[colb + fn * 32];
#pragma unroll
    for (int fm = 0; fm < 4; ++fm)
#pragma unroll
      for (int g = 0; g < 4; ++g)
#pragma unroll
        for (int rr = 0; rr < 4; ++rr) {
          float v = acc[fm][fn][g * 4 + rr] + b;
          if (relu) v = fmaxf(v, 0.0f);
          C[(size_t)(rowb + fm * 32 + g * 8 + rr) * N + colb + fn * 32] = f2bf(v);
        }
  }
}

// ---------- split-K GEMM2 (N=128): 128x128 tile, 3-stage, 1 barrier/step ----------
__global__ __launch_bounds__(256, 2) void k_gemm_sk(const u16* __restrict__ A, const u16* __restrict__ Bt,
                                                    float* __restrict__ Ep, int K, int Ksplit) {
  __shared__ __align__(16) u16 sm[24576];  // 3 x (A 128x32 | B 128x32) = 3x16KB
  const int tid = threadIdx.x;
  const int l = tid & 63, w = tid >> 6;
  const int wm = w >> 1, wn = w & 1;
  const int m0 = blockIdx.y * 128;
  const int split = blockIdx.x;
  const int k0s = split * Ksplit;

  const int kb = ((l & 3) ^ ((l >> 3) & 3)) * 16;
  const char* gA = (const char*)(A + (size_t)(m0 + w * 16 + (l >> 2)) * K + k0s) + kb;
  const char* gB = (const char*)(Bt + (size_t)(w * 16 + (l >> 2)) * K + k0s) + kb;
  const size_t radv = (size_t)64 * K * 2;

  auto issue = [&](int kcB, int stg) {
    char* base = (char*)sm + stg * 16384;
    char* dA = base + w * 1024 + l * 16;
    char* dB = base + 8192 + w * 1024 + l * 16;
    g2l16(gA + kcB, dA);
    g2l16(gA + radv + kcB, dA + 4096);
    g2l16(gB + kcB, dB);
    g2l16(gB + radv + kcB, dB + 4096);
  };

  const int lm = l & 31;
  const int c0 = l >> 5;
  const int sw = (lm >> 1) & 3;

  f32x16 acc[2][2] = {};

  auto compute = [&](int stg) {
    const u16* As = sm + stg * 8192;
    const u16* Bs = As + 4096;
#pragma unroll
    for (int t = 0; t < 2; ++t) {
      const int cc = (((t << 1) + c0) ^ sw) * 8;
      bf16x8 a2[2], b2[2];
#pragma unroll
      for (int fm = 0; fm < 2; ++fm) a2[fm] = *(const bf16x8*)(As + (wm * 64 + fm * 32 + lm) * 32 + cc);
#pragma unroll
      for (int fn = 0; fn < 2; ++fn) b2[fn] = *(const bf16x8*)(Bs + (wn * 64 + fn * 32 + lm) * 32 + cc);
#pragma unroll
      for (int fm = 0; fm < 2; ++fm)
#pragma unroll
        for (int fn = 0; fn < 2; ++fn)
          acc[fm][fn] = __builtin_amdgcn_mfma_f32_32x32x16_bf16(a2[fm], b2[fn],
                                                                acc[fm][fn], 0, 0, 0);
    }
  };

  const int NK = Ksplit >> 5;
  issue(0, 0);
  issue(64, 1);
  int st = 0;
  for (int kt = 0; kt < NK; ++kt) {
    if (kt + 1 < NK) asm volatile("s_waitcnt vmcnt(4)" ::: "memory");
    else             asm volatile("s_waitcnt vmcnt(0)" ::: "memory");
    asm volatile("s_barrier" ::: "memory");
    if (kt + 2 < NK) {
      int stp = st + 2; if (stp >= 3) stp -= 3;
      issue((kt + 2) * 64, stp);
    }
    compute(st);
    ++st; if (st == 3) st = 0;
  }

  const int colb = wn * 64 + lm;
  const int rowb = m0 + wm * 64 + 4 * c0;
#pragma unroll
  for (int fn = 0; fn < 2; ++fn)
#pragma unroll
    for (int fm = 0; fm < 2; ++fm)
#pragma unroll
      for (int g = 0; g < 4; ++g)
#pragma unroll
        for (int rr = 0; rr < 4; ++rr)
          Ep[((size_t)split * 8192 + rowb + fm * 32 + g * 8 + rr) * 128 + colb + fn * 32] =
              acc[fm][fn][g * 4 + rr];
}

// ---------- sum split-K partials + bias, L2-normalize rows, write bf16 f ----------
__global__ __launch_bounds__(256) void k_norm(const float* __restrict__ Ep,
                                              const float* __restrict__ b2, u16* __restrict__ F) {
  const int l = threadIdx.x & 63, w = threadIdx.x >> 6;
  const int row = blockIdx.x * 4 + w;
  const float2* base = (const float2*)Ep + (size_t)row * 64 + l;
  float x = 0.f, y = 0.f;
#pragma unroll
  for (int s = 0; s < 4; ++s) {
    float2 t = base[(size_t)s * (8192 * 64)];
    x += t.x; y += t.y;
  }
  x += b2[l * 2]; y += b2[l * 2 + 1];
  float sq = x * x + y * y;
#pragma unroll
  for (int off = 1; off < 64; off <<= 1) sq += __shfl_xor(sq, off);
  const float inv = 1.0f / sqrtf(sq);
  F[(size_t)row * 128 + l * 2] = f2bf(x * inv);
  F[(size_t)row * 128 + l * 2 + 1] = f2bf(y * inv);
}

// ---------- fused sim GEMM + fixed-max sumexp partials ----------
__global__ __launch_bounds__(256) void k_sim(const u16* __restrict__ F, float* __restrict__ Sp) {
  __shared__ __align__(16) u16 As[64 * 128];
  const int tid = threadIdx.x;
  const int l = tid & 63, w = tid >> 6;
  const int wm = w >> 1, wn = w & 1;
  const int row0 = blockIdx.y * 64;
  const int chunk = blockIdx.x;

#pragma unroll
  for (int j = 0; j < 4; ++j) {
    const int c = j * 4 + w;
    const int r = c * 4 + (l >> 4);
    const int cb = (l & 15) * 16;
    g2l16((const char*)(F + (size_t)(row0 + r) * 128) + cb, (char*)As + c * 1024 + l * 16);
  }
  asm volatile("s_waitcnt vmcnt(0)" ::: "memory");
  __syncthreads();

  bf16x8 af[2][4];
#pragma unroll
  for (int i = 0; i < 2; ++i)
#pragma unroll
    for (int s = 0; s < 4; ++s)
      af[i][s] = *(const bf16x8*)(As + (wm * 32 + i * 16 + (l & 15)) * 128 + s * 32 + (l >> 4) * 8);

  float runS[2][4] = {};
#pragma unroll 1
  for (int ct = 0; ct < 16; ++ct) {
    const int n0 = chunk * 2048 + ct * 128 + wn * 64;
    f32x4 acc[2][4] = {};
#pragma unroll
    for (int j = 0; j < 4; ++j) {
      const u16* bp = F + (size_t)(n0 + j * 16 + (l & 15)) * 128 + (l >> 4) * 8;
#pragma unroll
      for (int s = 0; s < 4; ++s) {
        bf16x8 bfr = *(const bf16x8*)(bp + s * 32);
        acc[0][j] = __builtin_amdgcn_mfma_f32_16x16x32_bf16(af[0][s], bfr, acc[0][j], 0, 0, 0);
        acc[1][j] = __builtin_amdgcn_mfma_f32_16x16x32_bf16(af[1][s], bfr, acc[1][j], 0, 0, 0);
      }
    }
#pragma unroll
    for (int i = 0; i < 2; ++i) {
      const int rb = row0 + wm * 32 + i * 16 + ((l >> 4) << 2);
#pragma unroll
      for (int r = 0; r < 4; ++r) {
        const int grow = rb + r;
        float sp = 0.f;
#pragma unroll
        for (int j = 0; j < 4; ++j) {
          const int gcol = n0 + j * 16 + (l & 15);
          float v = acc[i][j][r] * INVT;
          v = (gcol == grow) ? -1e30f : v;
          sp += __expf(v - INVT);
        }
        sp += __shfl_xor(sp, 1);
        sp += __shfl_xor(sp, 2);
        sp += __shfl_xor(sp, 4);
        sp += __shfl_xor(sp, 8);
        runS[i][r] += sp;
      }
    }
  }

  __syncthreads();
  float* red = (float*)As;
  if (wn == 0 && (l & 15) == 0) {
#pragma unroll
    for (int i = 0; i < 2; ++i)
#pragma unroll
      for (int r = 0; r < 4; ++r)
        red[wm * 32 + i * 16 + ((l >> 4) << 2) + r] = runS[i][r];
  }
  __syncthreads();
  if (wn == 1 && (l & 15) == 0) {
#pragma unroll
    for (int i = 0; i < 2; ++i)
#pragma unroll
      for (int r = 0; r < 4; ++r) {
        const int rr = wm * 32 + i * 16 + ((l >> 4) << 2) + r;
        Sp[(size_t)chunk * 8192 + row0 + rr] = red[rr] + runS[i][r];
      }
  }
}

// ---------- merge chunk partials, compute pos, reduce mean(lse - pos) ----------
__global__ __launch_bounds__(256) void k_combine(const float* __restrict__ Sp,
                                                 const u16* __restrict__ F,
                                                 float* __restrict__ out) {
  const int r = blockIdx.x * 256 + threadIdx.x;
  float S = Sp[r] + Sp[8192 + r] + Sp[2 * 8192 + r] + Sp[3 * 8192 + r];
  const float lse = INVT + logf(S);
  const int par = (r + 4096) & 8191;
  const u16* a = F + (size_t)r * 128;
  const u16* b = F + (size_t)par * 128;
  float dot = 0.f;
#pragma unroll 8
  for (int k = 0; k < 128; ++k) dot = fmaf(bf2f(a[k]), bf2f(b[k]), dot);
  float contrib = lse - dot * INVT;
#pragma unroll
  for (int off = 1; off < 64; off <<= 1) contrib += __shfl_xor(contrib, off);
  if ((threadIdx.x & 63) == 0) atomicAdd(out, contrib * (1.0f / 8192.0f));
}

extern "C" void kernel_launch(void* const* d_in, const int* in_sizes, int n_in,
                              void* d_out, int out_size, void* d_ws, size_t ws_size,
                              hipStream_t stream) {
  const float* input1 = (const float*)d_in[0];
  const float* input2 = (const float*)d_in[1];
  const float* W0 = (const float*)d_in[2];
  const float* b0 = (const float*)d_in[3];
  const float* W1 = (const float*)d_in[4];
  const float* b1 = (const float*)d_in[5];
  const float* W2 = (const float*)d_in[6];
  const float* b2 = (const float*)d_in[7];
  float* out = (float*)d_out;
  char* ws = (char*)d_ws;

  u16* Xb = (u16*)(ws + 0);              // [8192][2048] bf16; reused as H2
  u16* H1 = (u16*)(ws + 33554432);
  u16* W0T = (u16*)(ws + 67108864);
  u16* W1T = (u16*)(ws + 75497472);
  float* Ep = (float*)(ws + 67108864);   // overlays dead W0T/W1T
  u16* W2T = (u16*)(ws + 83886080);
  u16* Ff = (u16*)(ws + 84410368);
  float* Sp = (float*)(ws + 86507520);
  u16* H2 = Xb;

  hipMemsetAsync(d_out, 0, sizeof(float), stream);
  k_cvt2<<<16384, 256, 0, stream>>>(input1, input2, Xb);
  k_transpose2<<<dim3(32, 32, 2), 256, 0, stream>>>(W0, W0T, W1, W1T);
  k_transpose<<<dim3(2, 32), 256, 0, stream>>>(W2, W2T, 2048, 128);
  k_gemm<<<dim3(16, 32), 256, 0, stream>>>(Xb, W0T, b0, H1, 8192, 2048, 2048, 1);
  k_gemm<<<dim3(16, 32), 256, 0, stream>>>(H1, W1T, b1, H2, 8192, 2048, 2048, 0);
  k_gemm_sk<<<dim3(4, 64), 256, 0, stream>>>(H2, W2T, Ep, 2048, 512);
  k_norm<<<2048, 256, 0, stream>>>(Ep, b2, Ff);
  k_sim<<<dim3(4, 128), 256, 0, stream>>>(Ff, Sp);
  k_combine<<<32, 256, 0, stream>>>(Sp, Ff, out);
}

// Round 5
// 346.637 us; speedup vs baseline: 1.2997x; 1.0808x over previous
//
#include <hip/hip_runtime.h>
#include <stdint.h>

typedef float f32x4 __attribute__((ext_vector_type(4)));
typedef float f32x16 __attribute__((ext_vector_type(16)));
typedef __bf16 bf16x8 __attribute__((ext_vector_type(8)));
typedef unsigned short u16;
typedef unsigned int u32;

#define INVT 14.285714285714286f   // 1/0.07 ; also the fixed LSE max bound (cos<=1)
#define L2E  1.4426950408889634f

__device__ __forceinline__ u16 f2bf(float f) {
  u32 u = __float_as_uint(f);
  u32 r = (u + 0x7fffu + ((u >> 16) & 1u)) >> 16;
  return (u16)r;
}
__device__ __forceinline__ float bf2f(u16 h) { return __uint_as_float(((u32)h) << 16); }

// async global->LDS, 16B per lane (lane i lands at base + i*16)
__device__ __forceinline__ void g2l16(const void* g, void* l) {
  auto gp = reinterpret_cast<__attribute__((address_space(1))) uint32_t*>(
      reinterpret_cast<uintptr_t>(g));
  auto lp = reinterpret_cast<__attribute__((address_space(3))) uint32_t*>(
      reinterpret_cast<uintptr_t>(l));
  __builtin_amdgcn_global_load_lds(gp, lp, 16, 0, 0);
}

// ---------- fp32 -> bf16 convert, both inputs in one launch ----------
__global__ __launch_bounds__(256) void k_cvt2(const float* __restrict__ in1,
                                              const float* __restrict__ in2,
                                              u16* __restrict__ out) {
  int i = (blockIdx.x * 256 + threadIdx.x) * 4;
  float4 v;
  if (i < 8388608) v = *(const float4*)(in1 + i);
  else             v = *(const float4*)(in2 + (i - 8388608));
  ushort4 p;
  p.x = f2bf(v.x); p.y = f2bf(v.y); p.z = f2bf(v.z); p.w = f2bf(v.w);
  *(ushort4*)(out + i) = p;
}

// ---------- fp32 [R][C] -> bf16 [C][R] transpose (z selects W0/W1) ----------
__global__ __launch_bounds__(256) void k_transpose2(const float* __restrict__ w0,
                                                    u16* __restrict__ w0t,
                                                    const float* __restrict__ w1,
                                                    u16* __restrict__ w1t) {
  const float* in = blockIdx.z ? w1 : w0;
  u16* out = blockIdx.z ? w1t : w0t;
  const int R = 2048, C = 2048;
  __shared__ float t[64][65];
  const int r0 = blockIdx.y * 64, c0 = blockIdx.x * 64;
#pragma unroll
  for (int p = 0; p < 16; ++p) {
    int idx = p * 256 + threadIdx.x;
    int r = idx >> 6, c = idx & 63;
    t[r][c] = in[(size_t)(r0 + r) * C + (c0 + c)];
  }
  __syncthreads();
#pragma unroll
  for (int p = 0; p < 16; ++p) {
    int idx = p * 256 + threadIdx.x;
    int c = idx >> 6, r = idx & 63;
    out[(size_t)(c0 + c) * R + (r0 + r)] = f2bf(t[r][c]);
  }
}

__global__ __launch_bounds__(256) void k_transpose(const float* __restrict__ in,
                                                   u16* __restrict__ out, int R, int C) {
  __shared__ float t[64][65];
  const int r0 = blockIdx.y * 64, c0 = blockIdx.x * 64;
#pragma unroll
  for (int p = 0; p < 16; ++p) {
    int idx = p * 256 + threadIdx.x;
    int r = idx >> 6, c = idx & 63;
    t[r][c] = in[(size_t)(r0 + r) * C + (c0 + c)];
  }
  __syncthreads();
#pragma unroll
  for (int p = 0; p < 16; ++p) {
    int idx = p * 256 + threadIdx.x;
    int c = idx >> 6, r = idx & 63;
    out[(size_t)(c0 + c) * R + (r0 + r)] = f2bf(t[r][c]);
  }
}

// ---------- bf16 GEMM: C = op(A @ Bt^T + bias) ----------
// 256x128 tile, BK=32, 3-stage LDS pipeline, 1 barrier/k-step (round-4 struct).
__global__ __launch_bounds__(256, 2) void k_gemm(const u16* __restrict__ A, const u16* __restrict__ Bt,
                                                 const float* __restrict__ bias, u16* __restrict__ C,
                                                 int M, int N, int K, int relu) {
  __shared__ __align__(16) u16 sm[36864];
  const int tid = threadIdx.x;
  const int l = tid & 63, w = tid >> 6;
  const int wm = w >> 1, wn = w & 1;
  const int m0 = blockIdx.y * 256, n0 = blockIdx.x * 128;

  const int kb = ((l & 3) ^ ((l >> 3) & 3)) * 16;
  const char* gA = (const char*)(A + (size_t)(m0 + w * 64 + (l >> 2)) * K) + kb;
  const char* gB = (const char*)(Bt + (size_t)(n0 + w * 32 + (l >> 2)) * K) + kb;
  const size_t chRows = (size_t)16 * K * 2;

  auto issue = [&](int kcB, int stg) {
    char* base = (char*)sm + stg * 24576;
    char* dA = base + (w * 4) * 1024 + l * 16;
    char* dB = base + 16384 + (w * 2) * 1024 + l * 16;
#pragma unroll
    for (int j = 0; j < 4; ++j) g2l16(gA + j * chRows + kcB, dA + j * 1024);
#pragma unroll
    for (int j = 0; j < 2; ++j) g2l16(gB + j * chRows + kcB, dB + j * 1024);
  };

  const int lm = l & 31;
  const int c0 = l >> 5;
  const int sw = (lm >> 1) & 3;

  f32x16 acc[4][2] = {};

  auto compute = [&](int stg) {
    const u16* As = sm + stg * 12288;
    const u16* Bs = As + 8192;
#pragma unroll
    for (int t = 0; t < 2; ++t) {
      const int cc = (((t << 1) + c0) ^ sw) * 8;
      bf16x8 a4[4], b2[2];
#pragma unroll
      for (int fm = 0; fm < 4; ++fm)
        a4[fm] = *(const bf16x8*)(As + (wm * 128 + fm * 32 + lm) * 32 + cc);
#pragma unroll
      for (int fn = 0; fn < 2; ++fn)
        b2[fn] = *(const bf16x8*)(Bs + (wn * 64 + fn * 32 + lm) * 32 + cc);
#pragma unroll
      for (int fm = 0; fm < 4; ++fm)
#pragma unroll
        for (int fn = 0; fn < 2; ++fn)
          acc[fm][fn] = __builtin_amdgcn_mfma_f32_32x32x16_bf16(a4[fm], b2[fn],
                                                                acc[fm][fn], 0, 0, 0);
    }
  };

  const int NK = K >> 5;
  issue(0, 0);
  issue(64, 1);
  int st = 0;
  for (int kt = 0; kt < NK; ++kt) {
    if (kt + 1 < NK) asm volatile("s_waitcnt vmcnt(6)" ::: "memory");
    else             asm volatile("s_waitcnt vmcnt(0)" ::: "memory");
    asm volatile("s_barrier" ::: "memory");
    if (kt + 2 < NK) {
      int stp = st + 2; if (stp >= 3) stp -= 3;
      issue((kt + 2) * 64, stp);
    }
    compute(st);
    ++st; if (st == 3) st = 0;
  }

  const int colb = n0 + wn * 64 + lm;
  const int rowb = m0 + wm * 128 + 4 * c0;
#pragma unroll
  for (int fn = 0; fn < 2; ++fn) {
    const float b = bias[colb + fn * 32];
#pragma unroll
    for (int fm = 0; fm < 4; ++fm)
#pragma unroll
      for (int g = 0; g < 4; ++g)
#pragma unroll
        for (int rr = 0; rr < 4; ++rr) {
          float v = acc[fm][fn][g * 4 + rr] + b;
          if (relu) v = fmaxf(v, 0.0f);
          C[(size_t)(rowb + fm * 32 + g * 8 + rr) * N + colb + fn * 32] = f2bf(v);
        }
  }
}

// ---------- split-K GEMM2 (N=128): 128x128 tile, 3-stage, 1 barrier/step ----------
__global__ __launch_bounds__(256, 2) void k_gemm_sk(const u16* __restrict__ A, const u16* __restrict__ Bt,
                                                    float* __restrict__ Ep, int K, int Ksplit) {
  __shared__ __align__(16) u16 sm[24576];
  const int tid = threadIdx.x;
  const int l = tid & 63, w = tid >> 6;
  const int wm = w >> 1, wn = w & 1;
  const int m0 = blockIdx.y * 128;
  const int split = blockIdx.x;
  const int k0s = split * Ksplit;

  const int kb = ((l & 3) ^ ((l >> 3) & 3)) * 16;
  const char* gA = (const char*)(A + (size_t)(m0 + w * 16 + (l >> 2)) * K + k0s) + kb;
  const char* gB = (const char*)(Bt + (size_t)(w * 16 + (l >> 2)) * K + k0s) + kb;
  const size_t radv = (size_t)64 * K * 2;

  auto issue = [&](int kcB, int stg) {
    char* base = (char*)sm + stg * 16384;
    char* dA = base + w * 1024 + l * 16;
    char* dB = base + 8192 + w * 1024 + l * 16;
    g2l16(gA + kcB, dA);
    g2l16(gA + radv + kcB, dA + 4096);
    g2l16(gB + kcB, dB);
    g2l16(gB + radv + kcB, dB + 4096);
  };

  const int lm = l & 31;
  const int c0 = l >> 5;
  const int sw = (lm >> 1) & 3;

  f32x16 acc[2][2] = {};

  auto compute = [&](int stg) {
    const u16* As = sm + stg * 8192;
    const u16* Bs = As + 4096;
#pragma unroll
    for (int t = 0; t < 2; ++t) {
      const int cc = (((t << 1) + c0) ^ sw) * 8;
      bf16x8 a2[2], b2[2];
#pragma unroll
      for (int fm = 0; fm < 2; ++fm) a2[fm] = *(const bf16x8*)(As + (wm * 64 + fm * 32 + lm) * 32 + cc);
#pragma unroll
      for (int fn = 0; fn < 2; ++fn) b2[fn] = *(const bf16x8*)(Bs + (wn * 64 + fn * 32 + lm) * 32 + cc);
#pragma unroll
      for (int fm = 0; fm < 2; ++fm)
#pragma unroll
        for (int fn = 0; fn < 2; ++fn)
          acc[fm][fn] = __builtin_amdgcn_mfma_f32_32x32x16_bf16(a2[fm], b2[fn],
                                                                acc[fm][fn], 0, 0, 0);
    }
  };

  const int NK = Ksplit >> 5;
  issue(0, 0);
  issue(64, 1);
  int st = 0;
  for (int kt = 0; kt < NK; ++kt) {
    if (kt + 1 < NK) asm volatile("s_waitcnt vmcnt(4)" ::: "memory");
    else             asm volatile("s_waitcnt vmcnt(0)" ::: "memory");
    asm volatile("s_barrier" ::: "memory");
    if (kt + 2 < NK) {
      int stp = st + 2; if (stp >= 3) stp -= 3;
      issue((kt + 2) * 64, stp);
    }
    compute(st);
    ++st; if (st == 3) st = 0;
  }

  const int colb = wn * 64 + lm;
  const int rowb = m0 + wm * 64 + 4 * c0;
#pragma unroll
  for (int fn = 0; fn < 2; ++fn)
#pragma unroll
    for (int fm = 0; fm < 2; ++fm)
#pragma unroll
      for (int g = 0; g < 4; ++g)
#pragma unroll
        for (int rr = 0; rr < 4; ++rr)
          Ep[((size_t)split * 8192 + rowb + fm * 32 + g * 8 + rr) * 128 + colb + fn * 32] =
              acc[fm][fn][g * 4 + rr];
}

// ---------- sum split-K partials + bias, L2-normalize rows, write bf16 f ----------
__global__ __launch_bounds__(256) void k_norm(const float* __restrict__ Ep,
                                              const float* __restrict__ b2, u16* __restrict__ F) {
  const int l = threadIdx.x & 63, w = threadIdx.x >> 6;
  const int row = blockIdx.x * 4 + w;
  const float2* base = (const float2*)Ep + (size_t)row * 64 + l;
  float x = 0.f, y = 0.f;
#pragma unroll
  for (int s = 0; s < 4; ++s) {
    float2 t = base[(size_t)s * (8192 * 64)];
    x += t.x; y += t.y;
  }
  x += b2[l * 2]; y += b2[l * 2 + 1];
  float sq = x * x + y * y;
#pragma unroll
  for (int off = 1; off < 64; off <<= 1) sq += __shfl_xor(sq, off);
  const float inv = 1.0f / sqrtf(sq);
  F[(size_t)row * 128 + l * 2] = f2bf(x * inv);
  F[(size_t)row * 128 + l * 2 + 1] = f2bf(y * inv);
}

// ---------- fused sim GEMM + fixed-max sumexp, register-cached A ----------
// grid (8 col-chunks of 1024, 64 row-tiles of 128). K=128 entirely in regs:
// each wave holds its A-frags (2x8 bf16x8) for all panels; B-panels (128x128)
// stream through a 2-buffer LDS pipeline (A's LDS region recycled as buf 1).
// LDS 64KB -> 2 blocks/CU; VGPR ~200 -> 2 waves/SIMD. 1 barrier per panel.
// Sp[chunk][8192] = sum_j exp(sim/T - INVT) over chunk cols, diag excluded.
__global__ __launch_bounds__(256, 2) void k_sim(const u16* __restrict__ F, float* __restrict__ Sp) {
  __shared__ __align__(16) u16 sm[32768];  // [B0 32KB][A/B1 32KB]
  const int tid = threadIdx.x;
  const int l = tid & 63, w = tid >> 6;
  const int wm = w >> 1, wn = w & 1;
  const int lm = l & 31, c0 = l >> 5;
  const int r0 = blockIdx.y * 128;
  const int cb0 = blockIdx.x * 1024;

  u16* B0 = sm;
  u16* AB1 = sm + 16384;

  // stage a 128x128 u16 panel, swizzled: phys 16B chunk c holds logical c^(row&7)
  const int srow0 = tid >> 4;      // 0..15
  const int schunk = tid & 15;
  auto stage = [&](const u16* src, u16* dst) {
#pragma unroll
    for (int j = 0; j < 8; ++j) {
      const int row = j * 16 + srow0;
      const int lc = schunk ^ (row & 7);
      g2l16((const char*)(src + (size_t)row * 128) + lc * 16,
            (char*)dst + j * 4096 + tid * 16);
    }
  };

  // ---- prologue: stage A rows, load A-frags into registers ----
  stage(F + (size_t)r0 * 128, AB1);
  asm volatile("s_waitcnt vmcnt(0)" ::: "memory");
  __syncthreads();

  bf16x8 a[2][8];
#pragma unroll
  for (int fm = 0; fm < 2; ++fm) {
    const int ra = wm * 64 + fm * 32 + lm;
#pragma unroll
    for (int kf = 0; kf < 8; ++kf)
      a[fm][kf] = *(const bf16x8*)(AB1 + ra * 128 + (((kf << 1) + c0) ^ (ra & 7)) * 8);
  }
  asm volatile("s_waitcnt lgkmcnt(0)" ::: "memory");

  stage(F + (size_t)cb0 * 128, B0);  // panel 0

  const float S2 = INVT * L2E;
  const int rB = wn * 64 + lm;           // B-frag base row (fn adds 32)
  f32x16 runS[2] = {};

#pragma unroll 1
  for (int p = 0; p < 8; ++p) {
    asm volatile("s_waitcnt vmcnt(0)" ::: "memory");
    asm volatile("s_barrier" ::: "memory");
    if (p < 7) stage(F + (size_t)(cb0 + (p + 1) * 128) * 128, (p & 1) ? B0 : AB1);
    const u16* Bs = (p & 1) ? AB1 : B0;

    f32x16 acc[2][2] = {};
#pragma unroll
    for (int kf = 0; kf < 8; ++kf) {
      const int kc = (kf << 1) + c0;
      bf16x8 b0v = *(const bf16x8*)(Bs + rB * 128 + (kc ^ (rB & 7)) * 8);
      bf16x8 b1v = *(const bf16x8*)(Bs + (rB + 32) * 128 + (kc ^ ((rB + 32) & 7)) * 8);
      acc[0][0] = __builtin_amdgcn_mfma_f32_32x32x16_bf16(a[0][kf], b0v, acc[0][0], 0, 0, 0);
      acc[0][1] = __builtin_amdgcn_mfma_f32_32x32x16_bf16(a[0][kf], b1v, acc[0][1], 0, 0, 0);
      acc[1][0] = __builtin_amdgcn_mfma_f32_32x32x16_bf16(a[1][kf], b0v, acc[1][0], 0, 0, 0);
      acc[1][1] = __builtin_amdgcn_mfma_f32_32x32x16_bf16(a[1][kf], b1v, acc[1][1], 0, 0, 0);
    }

    // epilogue: runS[fm][r] += exp2((acc-1)*S2); diag zeroed in its panel
    const int cp = cb0 + p * 128;
    if (cp == r0) {
#pragma unroll
      for (int fm = 0; fm < 2; ++fm)
#pragma unroll
        for (int fn = 0; fn < 2; ++fn) {
          const int rcol = wn * 64 + fn * 32 + lm;
#pragma unroll
          for (int r = 0; r < 16; ++r) {
            const int rrow = wm * 64 + fm * 32 + (r & 3) + 8 * (r >> 2) + 4 * c0;
            float e = exp2f(fmaf(acc[fm][fn][r], S2, -S2));
            if (rrow == rcol) e = 0.f;
            runS[fm][r] += e;
          }
        }
    } else {
#pragma unroll
      for (int fm = 0; fm < 2; ++fm)
#pragma unroll
        for (int fn = 0; fn < 2; ++fn)
#pragma unroll
          for (int r = 0; r < 16; ++r)
            runS[fm][r] += exp2f(fmaf(acc[fm][fn][r], S2, -S2));
    }
  }

  // ---- reduce across the 32 lm lanes (rows identical within a c0-half) ----
#pragma unroll
  for (int fm = 0; fm < 2; ++fm)
#pragma unroll
    for (int r = 0; r < 16; ++r) {
      float s = runS[fm][r];
      s += __shfl_xor(s, 1);
      s += __shfl_xor(s, 2);
      s += __shfl_xor(s, 4);
      s += __shfl_xor(s, 8);
      s += __shfl_xor(s, 16);
      runS[fm][r] = s;
    }

  __syncthreads();
  float* red = (float*)sm;  // 128 floats
  if (wn == 0) {
    if (lm == 0) {
#pragma unroll
      for (int fm = 0; fm < 2; ++fm)
#pragma unroll
        for (int r = 0; r < 16; ++r)
          red[wm * 64 + fm * 32 + (r & 3) + 8 * (r >> 2) + 4 * c0] = runS[fm][r];
    }
  }
  __syncthreads();
  if (wn == 1 && lm == 0) {
#pragma unroll
    for (int fm = 0; fm < 2; ++fm)
#pragma unroll
      for (int r = 0; r < 16; ++r) {
        const int rr = wm * 64 + fm * 32 + (r & 3) + 8 * (r >> 2) + 4 * c0;
        Sp[(size_t)blockIdx.x * 8192 + r0 + rr] = red[rr] + runS[fm][r];
      }
  }
}

// ---------- merge chunk partials, compute pos, reduce mean(lse - pos) ----------
__global__ __launch_bounds__(256) void k_combine(const float* __restrict__ Sp,
                                                 const u16* __restrict__ F,
                                                 float* __restrict__ out) {
  const int r = blockIdx.x * 256 + threadIdx.x;
  float S = 0.f;
#pragma unroll
  for (int c = 0; c < 8; ++c) S += Sp[c * 8192 + r];
  const float lse = INVT + logf(S);
  const int par = (r + 4096) & 8191;
  const u16* a = F + (size_t)r * 128;
  const u16* b = F + (size_t)par * 128;
  float dot = 0.f;
#pragma unroll 8
  for (int k = 0; k < 128; ++k) dot = fmaf(bf2f(a[k]), bf2f(b[k]), dot);
  float contrib = lse - dot * INVT;
#pragma unroll
  for (int off = 1; off < 64; off <<= 1) contrib += __shfl_xor(contrib, off);
  if ((threadIdx.x & 63) == 0) atomicAdd(out, contrib * (1.0f / 8192.0f));
}

extern "C" void kernel_launch(void* const* d_in, const int* in_sizes, int n_in,
                              void* d_out, int out_size, void* d_ws, size_t ws_size,
                              hipStream_t stream) {
  const float* input1 = (const float*)d_in[0];
  const float* input2 = (const float*)d_in[1];
  const float* W0 = (const float*)d_in[2];
  const float* b0 = (const float*)d_in[3];
  const float* W1 = (const float*)d_in[4];
  const float* b1 = (const float*)d_in[5];
  const float* W2 = (const float*)d_in[6];
  const float* b2 = (const float*)d_in[7];
  float* out = (float*)d_out;
  char* ws = (char*)d_ws;

  u16* Xb = (u16*)(ws + 0);              // [8192][2048] bf16; reused as H2
  u16* H1 = (u16*)(ws + 33554432);
  u16* W0T = (u16*)(ws + 67108864);
  u16* W1T = (u16*)(ws + 75497472);
  float* Ep = (float*)(ws + 67108864);   // overlays dead W0T/W1T
  u16* W2T = (u16*)(ws + 83886080);
  float* Sp = (float*)(ws + 83886080);   // [8][8192] fp32, overlays dead W2T
  u16* Ff = (u16*)(ws + 84410368);
  u16* H2 = Xb;

  hipMemsetAsync(d_out, 0, sizeof(float), stream);
  k_cvt2<<<16384, 256, 0, stream>>>(input1, input2, Xb);
  k_transpose2<<<dim3(32, 32, 2), 256, 0, stream>>>(W0, W0T, W1, W1T);
  k_transpose<<<dim3(2, 32), 256, 0, stream>>>(W2, W2T, 2048, 128);
  k_gemm<<<dim3(16, 32), 256, 0, stream>>>(Xb, W0T, b0, H1, 8192, 2048, 2048, 1);
  k_gemm<<<dim3(16, 32), 256, 0, stream>>>(H1, W1T, b1, H2, 8192, 2048, 2048, 0);
  k_gemm_sk<<<dim3(4, 64), 256, 0, stream>>>(H2, W2T, Ep, 2048, 512);
  k_norm<<<2048, 256, 0, stream>>>(Ep, b2, Ff);
  k_sim<<<dim3(8, 64), 256, 0, stream>>>(Ff, Sp);
  k_combine<<<32, 256, 0, stream>>>(Sp, Ff, out);
}